// Round 2
// baseline (414.758 us; speedup 1.0000x reference)
//
#include <hip/hip_runtime.h>

#define NCL 20000
#define DIN 128
#define HID 2048
#define SEVN 2000
#define TPM 0.1f
#define ENTC 0.01f

#define MPAD 20224          // 316 * 64
#define T64 316             // row tiles of 64 rows

// workspace byte offsets
#define WS_B2K   0
#define WS_W2K   256
#define WS_LOGIT 8448                    // MPAD floats -> ends 89344
#define WS_CDATA 89600                   // 20000 * 16B -> ends 409600
#define WS_ASTG  409600                  // MPAD*128*2  -> ends 5586944
#define WS_BSTG  5586944                 // 128*2048*2  -> ends 6111232

typedef __attribute__((ext_vector_type(8))) short short8;
typedef __attribute__((ext_vector_type(4))) float f32x4;

static __device__ __forceinline__ unsigned short f2bf(float f) {
    unsigned u = __float_as_uint(f);
    u += 0x7FFFu + ((u >> 16) & 1u);     // round-to-nearest-even
    return (unsigned short)(u >> 16);
}
static __device__ __forceinline__ unsigned pck(unsigned short a, unsigned short b) {
    return (unsigned)a | ((unsigned)b << 16);
}

// ---------- K1: w2k[j] = sum_e W2[j,e]*key[e]; also b2k = sum_e b2[e]*key[e] ----------
__global__ __launch_bounds__(256) void k_w2k(const float* __restrict__ W2,
                                             const float* __restrict__ b2,
                                             const float* __restrict__ key,
                                             float* __restrict__ w2k,
                                             float* __restrict__ b2k) {
    int wid  = blockIdx.x * 4 + (threadIdx.x >> 6);
    int lane = threadIdx.x & 63;
    const float4* key4 = (const float4*)key;
    float acc = 0.f;
    if (wid <= HID) {
        const float4* row4 = (const float4*)((wid < HID) ? (W2 + (size_t)wid * 2048) : b2);
        #pragma unroll
        for (int it = 0; it < 8; ++it) {
            int idx = it * 64 + lane;
            float4 a = row4[idx], k4 = key4[idx];
            acc += a.x * k4.x + a.y * k4.y + a.z * k4.z + a.w * k4.w;
        }
    }
    #pragma unroll
    for (int m = 1; m < 64; m <<= 1) acc += __shfl_xor(acc, m);
    if (lane == 0 && wid < HID) w2k[wid] = acc;
    if (lane == 0 && wid == HID) *b2k = acc;
}

// ---------- K2: stage fv -> bf16 in MFMA A-fragment order ----------
// layout: [tile64][s=4][c=4][lane=64][j=8]; row=tile*64+s*16+(l&15); k=c*32+(l>>4)*8+j
__global__ __launch_bounds__(256) void k_stageA(const float* __restrict__ fv,
                                                unsigned short* __restrict__ ast) {
    int g = blockIdx.x * 256 + threadIdx.x;
    if (g >= T64 * 1024) return;
    int l = g & 63, c = (g >> 6) & 3, s = (g >> 8) & 3, r = g >> 10;
    int row = r * 64 + s * 16 + (l & 15);
    int k0  = c * 32 + (l >> 4) * 8;
    uint4 o;
    if (row < NCL) {
        const float* p = fv + (size_t)row * DIN + k0;
        float4 f0 = *(const float4*)p;
        float4 f1 = *(const float4*)(p + 4);
        o.x = pck(f2bf(f0.x), f2bf(f0.y));
        o.y = pck(f2bf(f0.z), f2bf(f0.w));
        o.z = pck(f2bf(f1.x), f2bf(f1.y));
        o.w = pck(f2bf(f1.z), f2bf(f1.w));
    } else {
        o.x = o.y = o.z = o.w = 0u;
    }
    ((uint4*)ast)[g] = o;
}

// ---------- K3: stage W1 -> bf16 in MFMA B-fragment order ----------
// layout: [ct=128][c=4][lane=64][j=8]; k=c*32+(l>>4)*8+j; col=ct*16+(l&15)
__global__ __launch_bounds__(256) void k_stageB(const float* __restrict__ W1,
                                                unsigned short* __restrict__ bst) {
    int g = blockIdx.x * 256 + threadIdx.x;     // 32768 total
    int l = g & 63, c = (g >> 6) & 3, ct = g >> 8;
    int col = ct * 16 + (l & 15);
    int kb  = c * 32 + (l >> 4) * 8;
    unsigned short v[8];
    #pragma unroll
    for (int j = 0; j < 8; ++j) v[j] = f2bf(W1[(size_t)(kb + j) * HID + col]);
    uint4 o;
    o.x = pck(v[0], v[1]); o.y = pck(v[2], v[3]);
    o.z = pck(v[4], v[5]); o.w = pck(v[6], v[7]);
    ((uint4*)bst)[g] = o;
}

// ---------- K4: logits = relu(fv@W1 + b1) @ w2k + b2k, fused ----------
// block: 512 thr = 8 waves; block owns 64 rows; wave w owns cols [w*256, w*256+256)
__global__ __launch_bounds__(512) void k_gemm(const unsigned short* __restrict__ ast,
                                              const unsigned short* __restrict__ bst,
                                              const float* __restrict__ b1,
                                              const float* __restrict__ w2k,
                                              const float* __restrict__ b2k,
                                              float* __restrict__ logits) {
    int blk = blockIdx.x;
    int tid = threadIdx.x;
    int w = tid >> 6, l = tid & 63;
    int colg = l & 15, kg = l >> 4;

    const short8* A8 = (const short8*)ast;
    const short8* B8 = (const short8*)bst;

    short8 afrag[4][4];
    #pragma unroll
    for (int s = 0; s < 4; ++s) {
        #pragma unroll
        for (int c = 0; c < 4; ++c)
            afrag[s][c] = A8[((((blk * 4 + s) * 4) + c) << 6) + l];
    }

    float acc[4][4];
    #pragma unroll
    for (int s = 0; s < 4; ++s)
        #pragma unroll
        for (int r = 0; r < 4; ++r) acc[s][r] = 0.f;

    int ct0 = w * 16;
    for (int t = 0; t < 16; ++t) {
        int ct = ct0 + t;
        short8 bfr[4];
        #pragma unroll
        for (int c = 0; c < 4; ++c) bfr[c] = B8[((ct * 4 + c) << 6) + l];
        int col = ct * 16 + colg;
        float b1v = b1[col];
        float wkv = w2k[col];
        #pragma unroll
        for (int s = 0; s < 4; ++s) {
            f32x4 d = {0.f, 0.f, 0.f, 0.f};
            #pragma unroll
            for (int c = 0; c < 4; ++c)
                d = __builtin_amdgcn_mfma_f32_16x16x32_bf16(afrag[s][c], bfr[c], d, 0, 0, 0);
            #pragma unroll
            for (int r = 0; r < 4; ++r) {
                float h = d[r] + b1v;
                h = h > 0.f ? h : 0.f;
                acc[s][r] += h * wkv;
            }
        }
    }

    __shared__ float red[8][64];
    #pragma unroll
    for (int s = 0; s < 4; ++s) {
        #pragma unroll
        for (int r = 0; r < 4; ++r) {
            float a = acc[s][r];
            a += __shfl_xor(a, 1);
            a += __shfl_xor(a, 2);
            a += __shfl_xor(a, 4);
            a += __shfl_xor(a, 8);
            if (colg == 0) red[w][s * 16 + kg * 4 + r] = a;
        }
    }
    __syncthreads();
    if (tid < 64) {
        float sum = *b2k;
        #pragma unroll
        for (int ww = 0; ww < 8; ++ww) sum += red[ww][tid];
        logits[blk * 64 + tid] = sum;
    }
}

// ---------- K5: per-clause packed data {exp(l), exp(l)*l, good?l:0, good?1:0} ----------
__global__ __launch_bounds__(256) void k_clause(const float* __restrict__ logits,
                                                const int* __restrict__ good,
                                                float4* __restrict__ cd) {
    int i = blockIdx.x * 256 + threadIdx.x;
    if (i >= NCL) return;
    float lg = logits[i];
    float e = expf(lg);                  // global shift 0: logits are O(+-4)
    bool g = good[i] != 0;
    cd[i] = make_float4(e, e * lg, g ? lg : 0.f, g ? 1.f : 0.f);
}

// ---------- K6: one block per SEL event; masked reductions + scalar epilogue ----------
// mask is int32 per element (bool -> int conversion by harness)
__global__ __launch_bounds__(256) void k_events(const unsigned* __restrict__ maski,
                                                const float4* __restrict__ cd,
                                                const float* __restrict__ logits,
                                                const float* __restrict__ times,
                                                const int* __restrict__ sel,
                                                float* __restrict__ out) {
    int s = blockIdx.x;
    int t = threadIdx.x;
    const uint4* mrow = (const uint4*)(maski + (size_t)s * NCL);
    float Z = 0.f, X = 0.f, cnt = 0.f, ng = 0.f, sg = 0.f;
    for (int i = t; i < NCL / 4; i += 256) {      // 5000 uint4 = 20000 int flags
        uint4 m = mrow[i];
        int base = i * 4;
        if (m.x) { float4 c = cd[base + 0]; Z += c.x; X += c.y; sg += c.z; ng += c.w; cnt += 1.f; }
        if (m.y) { float4 c = cd[base + 1]; Z += c.x; X += c.y; sg += c.z; ng += c.w; cnt += 1.f; }
        if (m.z) { float4 c = cd[base + 2]; Z += c.x; X += c.y; sg += c.z; ng += c.w; cnt += 1.f; }
        if (m.w) { float4 c = cd[base + 3]; Z += c.x; X += c.y; sg += c.z; ng += c.w; cnt += 1.f; }
    }
    #pragma unroll
    for (int m = 1; m < 64; m <<= 1) {
        Z   += __shfl_xor(Z, m);
        X   += __shfl_xor(X, m);
        cnt += __shfl_xor(cnt, m);
        ng  += __shfl_xor(ng, m);
        sg  += __shfl_xor(sg, m);
    }
    __shared__ float red[4][5];
    int lane = t & 63, w = t >> 6;
    if (lane == 0) {
        red[w][0] = Z; red[w][1] = X; red[w][2] = cnt; red[w][3] = ng; red[w][4] = sg;
    }
    __syncthreads();
    if (t == 0) {
        Z   = red[0][0] + red[1][0] + red[2][0] + red[3][0];
        X   = red[0][1] + red[1][1] + red[2][1] + red[3][1];
        cnt = red[0][2] + red[1][2] + red[2][2] + red[3][2];
        ng  = red[0][3] + red[1][3] + red[2][3] + red[3][3];
        sg  = red[0][4] + red[1][4] + red[2][4] + red[3][4];
        float L = logf(Z);
        if (ng > 0.5f) {
            atomicAdd(out + 0, L - sg / ng);
            atomicAdd(out + 1, 1.f);
        }
        float tm = times[s];
        float slg = logits[sel[s]];
        atomicAdd(out + 2, TPM * tm * (slg - L));
        atomicAdd(out + 3, tm);
        atomicAdd(out + 4, ENTC * ((X / Z - L) / logf(cnt)));
        if (s == 0) out[5] = (float)SEVN;
    }
}

extern "C" void kernel_launch(void* const* d_in, const int* in_sizes, int n_in,
                              void* d_out, int out_size, void* d_ws, size_t ws_size,
                              hipStream_t stream) {
    const float* fv    = (const float*)d_in[0];
    const float* W1    = (const float*)d_in[1];
    const float* b1    = (const float*)d_in[2];
    const float* W2    = (const float*)d_in[3];
    const float* b2    = (const float*)d_in[4];
    const float* key   = (const float*)d_in[5];
    const float* times = (const float*)d_in[6];
    const unsigned* mask = (const unsigned*)d_in[7];   // bool -> int32
    const int* good    = (const int*)d_in[8];          // bool -> int32
    const int* sel     = (const int*)d_in[9];
    float* out = (float*)d_out;
    char* ws = (char*)d_ws;

    float* w2k    = (float*)(ws + WS_W2K);
    float* b2k    = (float*)(ws + WS_B2K);
    float* logits = (float*)(ws + WS_LOGIT);
    float4* cdata = (float4*)(ws + WS_CDATA);
    unsigned short* ast = (unsigned short*)(ws + WS_ASTG);
    unsigned short* bst = (unsigned short*)(ws + WS_BSTG);

    hipMemsetAsync(d_out, 0, 6 * sizeof(float), stream);
    k_w2k  <<<513, 256, 0, stream>>>(W2, b2, key, w2k, b2k);
    k_stageA<<<(T64 * 1024) / 256, 256, 0, stream>>>(fv, ast);
    k_stageB<<<128, 256, 0, stream>>>(W1, bst);
    k_gemm <<<T64, 512, 0, stream>>>(ast, bst, b1, w2k, b2k, logits);
    k_clause<<<(NCL + 255) / 256, 256, 0, stream>>>(logits, good, cdata);
    k_events<<<SEVN, 256, 0, stream>>>(mask, cdata, logits, times, sel, out);
}

// Round 3
// 327.892 us; speedup vs baseline: 1.2649x; 1.2649x over previous
//
#include <hip/hip_runtime.h>

#define NCL 20000
#define DIN 128
#define HID 2048
#define SEVN 2000
#define TPM 0.1f
#define ENTC 0.01f

#define MPAD 20224          // 316 * 64
#define T64 316             // row tiles of 64 rows

#define NWORD 625           // 32-bit mask words per event (20000/32)
#define CWORDS 5            // words per chunk
#define NCHUNK 125          // 125 * 5 * 32 = 20000 exactly
#define EGRP 8              // event-groups of 256 (2048 slots)
#define SPAD 2048

// workspace byte offsets
#define WS_B2K   0
#define WS_W2K   256
#define WS_LOGIT 8448                    // MPAD floats -> 89344
#define WS_CDATA 89600                   // 20000*16B -> 409600
#define WS_ASTG  409600                  // MPAD*128*2 -> 5586944
#define WS_BSTG  5586944                 // 128*2048*2 -> 6111232
#define WS_PACK  6111232                 // 2000*625*4 = 5000000 -> 11111232
#define WS_PART  11111232                // 125*5*2048*4 = 5120000 -> 16231232

// fused streamer block ranges
#define NB_PACK 4883                     // ceil(2000*625/256)
#define NB_SA   1264                     // T64*1024/256
#define NB_SB   128
#define NB_WK   513

typedef __attribute__((ext_vector_type(8))) short short8;
typedef __attribute__((ext_vector_type(4))) float f32x4;

static __device__ __forceinline__ unsigned short f2bf(float f) {
    unsigned u = __float_as_uint(f);
    u += 0x7FFFu + ((u >> 16) & 1u);     // round-to-nearest-even
    return (unsigned short)(u >> 16);
}
static __device__ __forceinline__ unsigned pck(unsigned short a, unsigned short b) {
    return (unsigned)a | ((unsigned)b << 16);
}

// ---------- fused streamer: mask bit-pack + stageA + stageB + w2k ----------
__global__ __launch_bounds__(256) void k_stream(const unsigned* __restrict__ mask,
                                                unsigned* __restrict__ packed,
                                                const float* __restrict__ fv,
                                                unsigned short* __restrict__ ast,
                                                const float* __restrict__ W1,
                                                unsigned short* __restrict__ bst,
                                                const float* __restrict__ W2,
                                                const float* __restrict__ b2,
                                                const float* __restrict__ key,
                                                float* __restrict__ w2k,
                                                float* __restrict__ b2k) {
    int b = blockIdx.x;
    int t = threadIdx.x;

    if (b < NB_PACK) {
        // ---- role A: bit-pack mask (160MB -> 5MB) ----
        int id = b * 256 + t;                    // global word id
        if (id >= SEVN * NWORD) return;
        int s = id / NWORD;
        int w = id - s * NWORD;
        const uint4* p = (const uint4*)(mask + (size_t)s * NCL + w * 32);
        unsigned word = 0;
        #pragma unroll
        for (int q = 0; q < 8; ++q) {
            uint4 m = p[q];
            word |= (m.x ? 1u : 0u) << (q * 4 + 0);
            word |= (m.y ? 1u : 0u) << (q * 4 + 1);
            word |= (m.z ? 1u : 0u) << (q * 4 + 2);
            word |= (m.w ? 1u : 0u) << (q * 4 + 3);
        }
        packed[(size_t)s * NWORD + w] = word;
        return;
    }
    b -= NB_PACK;

    if (b < NB_SA) {
        // ---- role B: stage fv -> bf16 A-frag ----
        int g = b * 256 + t;
        int l = g & 63, c = (g >> 6) & 3, s = (g >> 8) & 3, r = g >> 10;
        int row = r * 64 + s * 16 + (l & 15);
        int k0  = c * 32 + (l >> 4) * 8;
        uint4 o;
        if (row < NCL) {
            const float* p = fv + (size_t)row * DIN + k0;
            float4 f0 = *(const float4*)p;
            float4 f1 = *(const float4*)(p + 4);
            o.x = pck(f2bf(f0.x), f2bf(f0.y));
            o.y = pck(f2bf(f0.z), f2bf(f0.w));
            o.z = pck(f2bf(f1.x), f2bf(f1.y));
            o.w = pck(f2bf(f1.z), f2bf(f1.w));
        } else {
            o.x = o.y = o.z = o.w = 0u;
        }
        ((uint4*)ast)[g] = o;
        return;
    }
    b -= NB_SA;

    if (b < NB_SB) {
        // ---- role C: stage W1 -> bf16 B-frag ----
        int g = b * 256 + t;
        int l = g & 63, c = (g >> 6) & 3, ct = g >> 8;
        int col = ct * 16 + (l & 15);
        int kb  = c * 32 + (l >> 4) * 8;
        unsigned short v[8];
        #pragma unroll
        for (int j = 0; j < 8; ++j) v[j] = f2bf(W1[(size_t)(kb + j) * HID + col]);
        uint4 o;
        o.x = pck(v[0], v[1]); o.y = pck(v[2], v[3]);
        o.z = pck(v[4], v[5]); o.w = pck(v[6], v[7]);
        ((uint4*)bst)[g] = o;
        return;
    }
    b -= NB_SB;

    // ---- role D: w2k = W2 @ key; b2k = b2 . key ----
    {
        int wid  = b * 4 + (t >> 6);
        int lane = t & 63;
        const float4* key4 = (const float4*)key;
        float acc = 0.f;
        if (wid <= HID) {
            const float4* row4 = (const float4*)((wid < HID) ? (W2 + (size_t)wid * 2048) : b2);
            #pragma unroll
            for (int it = 0; it < 8; ++it) {
                int idx = it * 64 + lane;
                float4 a = row4[idx], k4 = key4[idx];
                acc += a.x * k4.x + a.y * k4.y + a.z * k4.z + a.w * k4.w;
            }
        }
        #pragma unroll
        for (int m = 1; m < 64; m <<= 1) acc += __shfl_xor(acc, m);
        if (lane == 0 && wid < HID) w2k[wid] = acc;
        if (lane == 0 && wid == HID) *b2k = acc;
    }
}

// ---------- K4: logits = relu(fv@W1 + b1) @ w2k + b2k, fused clause epilogue ----------
__global__ __launch_bounds__(512) void k_gemm(const unsigned short* __restrict__ ast,
                                              const unsigned short* __restrict__ bst,
                                              const float* __restrict__ b1,
                                              const float* __restrict__ w2k,
                                              const float* __restrict__ b2k,
                                              const int* __restrict__ good,
                                              float* __restrict__ logits,
                                              float4* __restrict__ cd) {
    int blk = blockIdx.x;
    int tid = threadIdx.x;
    int w = tid >> 6, l = tid & 63;
    int colg = l & 15, kg = l >> 4;

    const short8* A8 = (const short8*)ast;
    const short8* B8 = (const short8*)bst;

    short8 afrag[4][4];
    #pragma unroll
    for (int s = 0; s < 4; ++s) {
        #pragma unroll
        for (int c = 0; c < 4; ++c)
            afrag[s][c] = A8[((((blk * 4 + s) * 4) + c) << 6) + l];
    }

    float acc[4][4];
    #pragma unroll
    for (int s = 0; s < 4; ++s)
        #pragma unroll
        for (int r = 0; r < 4; ++r) acc[s][r] = 0.f;

    int ct0 = w * 16;
    for (int t = 0; t < 16; ++t) {
        int ct = ct0 + t;
        short8 bfr[4];
        #pragma unroll
        for (int c = 0; c < 4; ++c) bfr[c] = B8[((ct * 4 + c) << 6) + l];
        int col = ct * 16 + colg;
        float b1v = b1[col];
        float wkv = w2k[col];
        #pragma unroll
        for (int s = 0; s < 4; ++s) {
            f32x4 d = {0.f, 0.f, 0.f, 0.f};
            #pragma unroll
            for (int c = 0; c < 4; ++c)
                d = __builtin_amdgcn_mfma_f32_16x16x32_bf16(afrag[s][c], bfr[c], d, 0, 0, 0);
            #pragma unroll
            for (int r = 0; r < 4; ++r) {
                float h = d[r] + b1v;
                h = h > 0.f ? h : 0.f;
                acc[s][r] += h * wkv;
            }
        }
    }

    __shared__ float red[8][64];
    #pragma unroll
    for (int s = 0; s < 4; ++s) {
        #pragma unroll
        for (int r = 0; r < 4; ++r) {
            float a = acc[s][r];
            a += __shfl_xor(a, 1);
            a += __shfl_xor(a, 2);
            a += __shfl_xor(a, 4);
            a += __shfl_xor(a, 8);
            if (colg == 0) red[w][s * 16 + kg * 4 + r] = a;
        }
    }
    __syncthreads();
    if (tid < 64) {
        float sum = *b2k;
        #pragma unroll
        for (int ww = 0; ww < 8; ++ww) sum += red[ww][tid];
        int row = blk * 64 + tid;
        logits[row] = sum;
        if (row < NCL) {
            float e = expf(sum);             // logits are O(+-5): exp safe in fp32
            bool g = good[row] != 0;
            cd[row] = make_float4(e, e * sum, g ? sum : 0.f, g ? 1.f : 0.f);
        }
    }
}

// ---------- K5: events — thread=event, chunked clauses, scalar cd loads ----------
__global__ __launch_bounds__(256) void k_events(const unsigned* __restrict__ packed,
                                                const float4* __restrict__ cd,
                                                float* __restrict__ part) {
    int chunk = blockIdx.x / EGRP;           // 0..124
    int eg    = blockIdx.x % EGRP;           // 0..7
    int s     = eg * 256 + threadIdx.x;      // 0..2047
    float Z = 0.f, X = 0.f, cnt = 0.f, ng = 0.f, sg = 0.f;
    if (s < SEVN) {
        int w0 = chunk * CWORDS;
        unsigned wv[CWORDS];
        #pragma unroll
        for (int w = 0; w < CWORDS; ++w)
            wv[w] = packed[(size_t)s * NWORD + w0 + w];
        #pragma unroll
        for (int w = 0; w < CWORDS; ++w) {
            int cbase = (w0 + w) * 32;
            #pragma unroll
            for (int b = 0; b < 32; ++b) {
                float4 c = cd[cbase + b];    // wave-uniform -> scalar load
                bool m = (wv[w] >> b) & 1u;
                Z   += m ? c.x : 0.f;
                X   += m ? c.y : 0.f;
                sg  += m ? c.z : 0.f;
                ng  += m ? c.w : 0.f;
                cnt += m ? 1.f : 0.f;
            }
        }
    }
    float* pp = part + (size_t)chunk * 5 * SPAD;
    pp[0 * SPAD + s] = Z;
    pp[1 * SPAD + s] = X;
    pp[2 * SPAD + s] = cnt;
    pp[3 * SPAD + s] = ng;
    pp[4 * SPAD + s] = sg;
}

// ---------- K6: final reduction + epilogue ----------
__global__ __launch_bounds__(256) void k_final(const float* __restrict__ part,
                                               const float* __restrict__ logits,
                                               const float* __restrict__ times,
                                               const int* __restrict__ sel,
                                               float* __restrict__ out) {
    int s = blockIdx.x * 256 + threadIdx.x;  // 0..2047
    bool live = s < SEVN;
    float Z = 0.f, X = 0.f, cnt = 0.f, ng = 0.f, sg = 0.f;
    if (live) {
        for (int c = 0; c < NCHUNK; ++c) {
            const float* pp = part + (size_t)c * 5 * SPAD;
            Z   += pp[0 * SPAD + s];
            X   += pp[1 * SPAD + s];
            cnt += pp[2 * SPAD + s];
            ng  += pp[3 * SPAD + s];
            sg  += pp[4 * SPAD + s];
        }
    }
    float gl = 0.f, ngs = 0.f, tl = 0.f, tv = 0.f, en = 0.f;
    if (live) {
        float L = logf(Z);
        if (ng > 0.5f) { gl = L - sg / ng; ngs = 1.f; }
        float tm = times[s];
        tl = TPM * tm * (logits[sel[s]] - L);
        tv = tm;
        en = ENTC * ((X / Z - L) / logf(cnt));
    }
    #pragma unroll
    for (int m = 1; m < 64; m <<= 1) {
        gl  += __shfl_xor(gl, m);
        ngs += __shfl_xor(ngs, m);
        tl  += __shfl_xor(tl, m);
        tv  += __shfl_xor(tv, m);
        en  += __shfl_xor(en, m);
    }
    if ((threadIdx.x & 63) == 0) {
        atomicAdd(out + 0, gl);
        atomicAdd(out + 1, ngs);
        atomicAdd(out + 2, tl);
        atomicAdd(out + 3, tv);
        atomicAdd(out + 4, en);
    }
    if (s == 0) out[5] = (float)SEVN;
}

extern "C" void kernel_launch(void* const* d_in, const int* in_sizes, int n_in,
                              void* d_out, int out_size, void* d_ws, size_t ws_size,
                              hipStream_t stream) {
    const float* fv    = (const float*)d_in[0];
    const float* W1    = (const float*)d_in[1];
    const float* b1    = (const float*)d_in[2];
    const float* W2    = (const float*)d_in[3];
    const float* b2    = (const float*)d_in[4];
    const float* key   = (const float*)d_in[5];
    const float* times = (const float*)d_in[6];
    const unsigned* mask = (const unsigned*)d_in[7];   // bool -> int32
    const int* good    = (const int*)d_in[8];          // bool -> int32
    const int* sel     = (const int*)d_in[9];
    float* out = (float*)d_out;
    char* ws = (char*)d_ws;

    float* w2k    = (float*)(ws + WS_W2K);
    float* b2k    = (float*)(ws + WS_B2K);
    float* logits = (float*)(ws + WS_LOGIT);
    float4* cdata = (float4*)(ws + WS_CDATA);
    unsigned short* ast = (unsigned short*)(ws + WS_ASTG);
    unsigned short* bst = (unsigned short*)(ws + WS_BSTG);
    unsigned* packed = (unsigned*)(ws + WS_PACK);
    float* part   = (float*)(ws + WS_PART);

    hipMemsetAsync(d_out, 0, 6 * sizeof(float), stream);
    k_stream<<<NB_PACK + NB_SA + NB_SB + NB_WK, 256, 0, stream>>>(
        mask, packed, fv, ast, W1, bst, W2, b2, key, w2k, b2k);
    k_gemm <<<T64, 512, 0, stream>>>(ast, bst, b1, w2k, b2k, good, logits, cdata);
    k_events<<<NCHUNK * EGRP, 256, 0, stream>>>(packed, cdata, part);
    k_final<<<SPAD / 256, 256, 0, stream>>>(part, logits, times, sel, out);
}

// Round 4
// 326.503 us; speedup vs baseline: 1.2703x; 1.0043x over previous
//
#include <hip/hip_runtime.h>

#define NCL 20000
#define DIN 128
#define HID 2048
#define SEVN 2000
#define TPM 0.1f
#define ENTC 0.01f

#define MPAD 20224          // 316 * 64
#define T64 316             // row tiles of 64 rows

#define NWORD 625           // 32-bit mask words per event (20000/32)
#define CWORDS 5            // words per chunk
#define NCHUNK 125          // 125 * 5 * 32 = 20000 exactly
#define EGRP 8              // event-groups of 256 (2048 slots)
#define SPAD 2048
#define NW_ITERS 156250     // 40,000,000 ints / 256 ints per wave-iter

// workspace byte offsets
#define WS_B2K   0
#define WS_W2K   256
#define WS_LOGIT 8448                    // MPAD floats -> 89344
#define WS_CDATA 89600                   // 20000*16B -> 409600
#define WS_ASTG  409600                  // MPAD*128*2 -> 5586944
#define WS_BSTG  5586944                 // 128*2048*2 -> 6111232
#define WS_PACK  6111232                 // 2000*625*4 = 5000000 -> 11111232
#define WS_PART  11111232                // 125*5*2048*4 = 5120000 -> 16231232

// fused streamer block ranges
#define NB_PACK 1024                     // ballot-pack, grid-stride (4096 waves)
#define NB_SA   1264                     // T64*1024/256
#define NB_SB   128
#define NB_WK   513

typedef __attribute__((ext_vector_type(8))) short short8;
typedef __attribute__((ext_vector_type(4))) float f32x4;

static __device__ __forceinline__ unsigned short f2bf(float f) {
    unsigned u = __float_as_uint(f);
    u += 0x7FFFu + ((u >> 16) & 1u);     // round-to-nearest-even
    return (unsigned short)(u >> 16);
}
static __device__ __forceinline__ unsigned pck(unsigned short a, unsigned short b) {
    return (unsigned)a | ((unsigned)b << 16);
}

// ---------- fused streamer: ballot mask-pack + stageA + stageB + w2k ----------
__global__ __launch_bounds__(256) void k_stream(const unsigned* __restrict__ mask,
                                                unsigned* __restrict__ packed,
                                                const float* __restrict__ fv,
                                                unsigned short* __restrict__ ast,
                                                const float* __restrict__ W1,
                                                unsigned short* __restrict__ bst,
                                                const float* __restrict__ W2,
                                                const float* __restrict__ b2,
                                                const float* __restrict__ key,
                                                float* __restrict__ w2k,
                                                float* __restrict__ b2k) {
    int b = blockIdx.x;
    int t = threadIdx.x;

    if (b < NB_PACK) {
        // ---- role A: ballot bit-pack of mask (160MB -> 5MB), fully coalesced ----
        int lane = t & 63;
        int wid  = b * 4 + (t >> 6);
        for (int it = wid; it < NW_ITERS; it += NB_PACK * 4) {
            size_t ibase = (size_t)it * 256;
            unsigned m0 = mask[ibase +   0 + lane];
            unsigned m1 = mask[ibase +  64 + lane];
            unsigned m2 = mask[ibase + 128 + lane];
            unsigned m3 = mask[ibase + 192 + lane];
            unsigned long long b0 = __ballot(m0 != 0);
            unsigned long long b1 = __ballot(m1 != 0);
            unsigned long long b2_ = __ballot(m2 != 0);
            unsigned long long b3 = __ballot(m3 != 0);
            if (lane < 8) {
                int q = lane >> 1;
                unsigned long long bq = (q == 0) ? b0 : (q == 1) ? b1 : (q == 2) ? b2_ : b3;
                unsigned v = (lane & 1) ? (unsigned)(bq >> 32) : (unsigned)bq;
                packed[(size_t)it * 8 + lane] = v;
            }
        }
        return;
    }
    b -= NB_PACK;

    if (b < NB_SA) {
        // ---- role B: stage fv -> bf16 A-frag ----
        int g = b * 256 + t;
        int l = g & 63, c = (g >> 6) & 3, s = (g >> 8) & 3, r = g >> 10;
        int row = r * 64 + s * 16 + (l & 15);
        int k0  = c * 32 + (l >> 4) * 8;
        uint4 o;
        if (row < NCL) {
            const float* p = fv + (size_t)row * DIN + k0;
            float4 f0 = *(const float4*)p;
            float4 f1 = *(const float4*)(p + 4);
            o.x = pck(f2bf(f0.x), f2bf(f0.y));
            o.y = pck(f2bf(f0.z), f2bf(f0.w));
            o.z = pck(f2bf(f1.x), f2bf(f1.y));
            o.w = pck(f2bf(f1.z), f2bf(f1.w));
        } else {
            o.x = o.y = o.z = o.w = 0u;
        }
        ((uint4*)ast)[g] = o;
        return;
    }
    b -= NB_SA;

    if (b < NB_SB) {
        // ---- role C: stage W1 -> bf16 B-frag ----
        int g = b * 256 + t;
        int l = g & 63, c = (g >> 6) & 3, ct = g >> 8;
        int col = ct * 16 + (l & 15);
        int kb  = c * 32 + (l >> 4) * 8;
        unsigned short v[8];
        #pragma unroll
        for (int j = 0; j < 8; ++j) v[j] = f2bf(W1[(size_t)(kb + j) * HID + col]);
        uint4 o;
        o.x = pck(v[0], v[1]); o.y = pck(v[2], v[3]);
        o.z = pck(v[4], v[5]); o.w = pck(v[6], v[7]);
        ((uint4*)bst)[g] = o;
        return;
    }
    b -= NB_SB;

    // ---- role D: w2k = W2 @ key; b2k = b2 . key ----
    {
        int wid  = b * 4 + (t >> 6);
        int lane = t & 63;
        const float4* key4 = (const float4*)key;
        float acc = 0.f;
        if (wid <= HID) {
            const float4* row4 = (const float4*)((wid < HID) ? (W2 + (size_t)wid * 2048) : b2);
            #pragma unroll
            for (int it = 0; it < 8; ++it) {
                int idx = it * 64 + lane;
                float4 a = row4[idx], k4 = key4[idx];
                acc += a.x * k4.x + a.y * k4.y + a.z * k4.z + a.w * k4.w;
            }
        }
        #pragma unroll
        for (int m = 1; m < 64; m <<= 1) acc += __shfl_xor(acc, m);
        if (lane == 0 && wid < HID) w2k[wid] = acc;
        if (lane == 0 && wid == HID) *b2k = acc;
    }
}

// ---------- K4: logits = relu(fv@W1 + b1) @ w2k + b2k, B-prefetch, fused clause epi ----------
__global__ __launch_bounds__(512) void k_gemm(const unsigned short* __restrict__ ast,
                                              const unsigned short* __restrict__ bst,
                                              const float* __restrict__ b1,
                                              const float* __restrict__ w2k,
                                              const float* __restrict__ b2k,
                                              const int* __restrict__ good,
                                              float* __restrict__ logits,
                                              float4* __restrict__ cd) {
    int blk = blockIdx.x;
    int tid = threadIdx.x;
    int w = tid >> 6, l = tid & 63;
    int colg = l & 15, kg = l >> 4;

    const short8* A8 = (const short8*)ast;
    const short8* B8 = (const short8*)bst;

    short8 afrag[4][4];
    #pragma unroll
    for (int s = 0; s < 4; ++s) {
        #pragma unroll
        for (int c = 0; c < 4; ++c)
            afrag[s][c] = A8[((((blk * 4 + s) * 4) + c) << 6) + l];
    }

    float acc[4][4];
    #pragma unroll
    for (int s = 0; s < 4; ++s)
        #pragma unroll
        for (int r = 0; r < 4; ++r) acc[s][r] = 0.f;

    int ct0 = w * 16;
    short8 bcur[4];
    #pragma unroll
    for (int c = 0; c < 4; ++c) bcur[c] = B8[((ct0 * 4 + c) << 6) + l];
    float b1c = b1[ct0 * 16 + colg];
    float wkc = w2k[ct0 * 16 + colg];

    for (int t = 0; t < 16; ++t) {
        short8 bnxt[4];
        float b1n = 0.f, wkn = 0.f;
        if (t < 15) {
            int ctn = ct0 + t + 1;
            #pragma unroll
            for (int c = 0; c < 4; ++c) bnxt[c] = B8[((ctn * 4 + c) << 6) + l];
            b1n = b1[ctn * 16 + colg];
            wkn = w2k[ctn * 16 + colg];
        }
        #pragma unroll
        for (int s = 0; s < 4; ++s) {
            f32x4 d = {0.f, 0.f, 0.f, 0.f};
            #pragma unroll
            for (int c = 0; c < 4; ++c)
                d = __builtin_amdgcn_mfma_f32_16x16x32_bf16(afrag[s][c], bcur[c], d, 0, 0, 0);
            #pragma unroll
            for (int r = 0; r < 4; ++r) {
                float h = d[r] + b1c;
                h = h > 0.f ? h : 0.f;
                acc[s][r] += h * wkc;
            }
        }
        if (t < 15) {
            #pragma unroll
            for (int c = 0; c < 4; ++c) bcur[c] = bnxt[c];
            b1c = b1n; wkc = wkn;
        }
    }

    __shared__ float red[8][64];
    #pragma unroll
    for (int s = 0; s < 4; ++s) {
        #pragma unroll
        for (int r = 0; r < 4; ++r) {
            float a = acc[s][r];
            a += __shfl_xor(a, 1);
            a += __shfl_xor(a, 2);
            a += __shfl_xor(a, 4);
            a += __shfl_xor(a, 8);
            if (colg == 0) red[w][s * 16 + kg * 4 + r] = a;
        }
    }
    __syncthreads();
    if (tid < 64) {
        float sum = *b2k;
        #pragma unroll
        for (int ww = 0; ww < 8; ++ww) sum += red[ww][tid];
        int row = blk * 64 + tid;
        logits[row] = sum;
        if (row < NCL) {
            float e = expf(sum);             // logits are O(+-5): exp safe in fp32
            bool g = good[row] != 0;
            cd[row] = make_float4(e, e * sum, g ? sum : 0.f, g ? 1.f : 0.f);
        }
    }
}

// ---------- K5: events — thread=event, chunked clauses, scalar cd loads ----------
__global__ __launch_bounds__(256) void k_events(const unsigned* __restrict__ packed,
                                                const float4* __restrict__ cd,
                                                float* __restrict__ part) {
    int chunk = blockIdx.x / EGRP;           // 0..124
    int eg    = blockIdx.x % EGRP;           // 0..7
    int s     = eg * 256 + threadIdx.x;      // 0..2047
    float Z = 0.f, X = 0.f, cnt = 0.f, ng = 0.f, sg = 0.f;
    if (s < SEVN) {
        int w0 = chunk * CWORDS;
        unsigned wv[CWORDS];
        #pragma unroll
        for (int w = 0; w < CWORDS; ++w)
            wv[w] = packed[(size_t)s * NWORD + w0 + w];
        #pragma unroll
        for (int w = 0; w < CWORDS; ++w) {
            int cbase = (w0 + w) * 32;
            #pragma unroll
            for (int b = 0; b < 32; ++b) {
                float4 c = cd[cbase + b];    // wave-uniform -> scalar load
                bool m = (wv[w] >> b) & 1u;
                Z   += m ? c.x : 0.f;
                X   += m ? c.y : 0.f;
                sg  += m ? c.z : 0.f;
                ng  += m ? c.w : 0.f;
                cnt += m ? 1.f : 0.f;
            }
        }
    }
    float* pp = part + (size_t)chunk * 5 * SPAD;
    pp[0 * SPAD + s] = Z;
    pp[1 * SPAD + s] = X;
    pp[2 * SPAD + s] = cnt;
    pp[3 * SPAD + s] = ng;
    pp[4 * SPAD + s] = sg;
}

// ---------- K6: final reduction + epilogue ----------
__global__ __launch_bounds__(256) void k_final(const float* __restrict__ part,
                                               const float* __restrict__ logits,
                                               const float* __restrict__ times,
                                               const int* __restrict__ sel,
                                               float* __restrict__ out) {
    int s = blockIdx.x * 256 + threadIdx.x;  // 0..2047
    bool live = s < SEVN;
    float Z = 0.f, X = 0.f, cnt = 0.f, ng = 0.f, sg = 0.f;
    if (live) {
        for (int c = 0; c < NCHUNK; ++c) {
            const float* pp = part + (size_t)c * 5 * SPAD;
            Z   += pp[0 * SPAD + s];
            X   += pp[1 * SPAD + s];
            cnt += pp[2 * SPAD + s];
            ng  += pp[3 * SPAD + s];
            sg  += pp[4 * SPAD + s];
        }
    }
    float gl = 0.f, ngs = 0.f, tl = 0.f, tv = 0.f, en = 0.f;
    if (live) {
        float L = logf(Z);
        if (ng > 0.5f) { gl = L - sg / ng; ngs = 1.f; }
        float tm = times[s];
        tl = TPM * tm * (logits[sel[s]] - L);
        tv = tm;
        en = ENTC * ((X / Z - L) / logf(cnt));
    }
    #pragma unroll
    for (int m = 1; m < 64; m <<= 1) {
        gl  += __shfl_xor(gl, m);
        ngs += __shfl_xor(ngs, m);
        tl  += __shfl_xor(tl, m);
        tv  += __shfl_xor(tv, m);
        en  += __shfl_xor(en, m);
    }
    if ((threadIdx.x & 63) == 0) {
        atomicAdd(out + 0, gl);
        atomicAdd(out + 1, ngs);
        atomicAdd(out + 2, tl);
        atomicAdd(out + 3, tv);
        atomicAdd(out + 4, en);
    }
    if (s == 0) out[5] = (float)SEVN;
}

extern "C" void kernel_launch(void* const* d_in, const int* in_sizes, int n_in,
                              void* d_out, int out_size, void* d_ws, size_t ws_size,
                              hipStream_t stream) {
    const float* fv    = (const float*)d_in[0];
    const float* W1    = (const float*)d_in[1];
    const float* b1    = (const float*)d_in[2];
    const float* W2    = (const float*)d_in[3];
    const float* b2    = (const float*)d_in[4];
    const float* key   = (const float*)d_in[5];
    const float* times = (const float*)d_in[6];
    const unsigned* mask = (const unsigned*)d_in[7];   // bool -> int32
    const int* good    = (const int*)d_in[8];          // bool -> int32
    const int* sel     = (const int*)d_in[9];
    float* out = (float*)d_out;
    char* ws = (char*)d_ws;

    float* w2k    = (float*)(ws + WS_W2K);
    float* b2k    = (float*)(ws + WS_B2K);
    float* logits = (float*)(ws + WS_LOGIT);
    float4* cdata = (float4*)(ws + WS_CDATA);
    unsigned short* ast = (unsigned short*)(ws + WS_ASTG);
    unsigned short* bst = (unsigned short*)(ws + WS_BSTG);
    unsigned* packed = (unsigned*)(ws + WS_PACK);
    float* part   = (float*)(ws + WS_PART);

    hipMemsetAsync(d_out, 0, 6 * sizeof(float), stream);
    k_stream<<<NB_PACK + NB_SA + NB_SB + NB_WK, 256, 0, stream>>>(
        mask, packed, fv, ast, W1, bst, W2, b2, key, w2k, b2k);
    k_gemm <<<T64, 512, 0, stream>>>(ast, bst, b1, w2k, b2k, good, logits, cdata);
    k_events<<<NCHUNK * EGRP, 256, 0, stream>>>(packed, cdata, part);
    k_final<<<SPAD / 256, 256, 0, stream>>>(part, logits, times, sel, out);
}